// Round 4
// baseline (185.983 us; speedup 1.0000x reference)
//
#include <hip/hip_runtime.h>
#include <math.h>

#define NB 256     // N nodes
#define CH 64      // C input features
#define OUTF 64    // O output features
#define GK 8       // GRID_SIZE + SPLINE_ORDER
#define UIN 128    // update-KAN input dim (C + O)
#define KU (UIN * 9)   // 1152 feature rows for update KAN
#define KU4 (KU / 4)   // 288

// workspace layout in floats
#define WS_MSG 0          // 512*64  = 32768
#define WS_W2U 32768      // 288*64*4 = 73728
// total 106496 floats = 416 KB

// device barrier state (zero-initialized at module load; epoch is
// monotonic across iterations, counters return to 0 after each use)
__device__ int g_cnt[256];   // 8 counters at stride 32 ints (128 B apart)
__device__ int g_sub;
__device__ int g_epoch;

__device__ __forceinline__ float silu(float v) {
    return v * __builtin_amdgcn_rcpf(1.0f + __expf(-v));
}

// Uniform cubic B-spline, knots t(m)=0.4m-2.2. Interval d=floor((r+2.2)*2.5),
// u=frac. 4 nonzero bases m=d-3..d. Out of grid -> d=11 (zeros).
__device__ __forceinline__ void spline4(float r, int& d, float4& v) {
    float p = fmaf(r, 2.5f, 5.5f);   // (r+2.2)*2.5
    float fd = floorf(p);
    d = (int)fd;
    float u = p - fd;
    if ((unsigned)d > 10u) d = 11;
    float um = 1.0f - u;
    float u2 = u * u, u3 = u2 * u;
    const float k6 = 1.0f / 6.0f;
    v.x = um * um * um * k6;
    v.y = (3.0f * u3 - 6.0f * u2 + 4.0f) * k6;
    v.z = (-3.0f * u3 + 3.0f * u2 + 3.0f * u + 1.0f) * k6;
    v.w = u3 * k6;
}

// Single fused kernel: grid = 512 blocks x 256 threads, 2 blocks/CU resident.
// Phase A (per block r): msg[r] with inline weight fold, cpad into own LDS,
// 1/512 slice of the W2U fold. Device barrier. Phase B: gat row r.
__global__ __launch_bounds__(256, 2) void fused_kernel(
    const float* __restrict__ x,     // (B, N, C)
    const int* __restrict__ adj,
    const float* __restrict__ fwb, const float* __restrict__ fws,
    const float* __restrict__ fwsc,
    const float* __restrict__ mwb, const float* __restrict__ mws,
    const float* __restrict__ mwsc,
    const float* __restrict__ uwb, const float* __restrict__ uws,
    const float* __restrict__ uwsc,
    float* __restrict__ ws,
    float* __restrict__ out) {
    const int tid = threadIdx.x;
    const int r = blockIdx.x;        // global row 0..511
    const int b = r >> 8, i = r & 255;

    __shared__ float4 cpad[CH][16];              // 16 KB, persists A->B
    __shared__ float4 xi4[16];                   // x_i row
    __shared__ float4 fb4[16];                   // fwb
    __shared__ __align__(16) char pool[11392];   // phase-aliased scratch

    // phase A views
    float* F2   = (float*)pool;                  // [64][16] features (4 KB)
    float* pmsg = (float*)(pool + 4096);         // [4][64] matvec partials
    // phase B views (F2/pmsg dead by then)
    float*  alpha = (float*)pool;                // [256]
    float*  comb  = (float*)(pool + 1024);       // [128]
    float*  Fu    = (float*)(pool + 1536);       // [1152]
    float4* part4 = (float4*)(pool + 6144);      // [16][16]
    float*  p2    = (float*)(pool + 10240);      // [4][64]
    float*  wred  = (float*)(pool + 11264);      // [4]

    // ================= PHASE A =================
    // msg features F2[c][0..7]=spline, [8]=silu (16-stride for b128 align)
    if (tid < CH) {
        float v = x[r * CH + tid];
        float* Fc = F2 + tid * 16;
#pragma unroll
        for (int g = 0; g < 8; ++g) Fc[g] = 0.0f;
        Fc[8] = silu(v);
        int d; float4 vv; spline4(v, d, vv);
#pragma unroll
        for (int k = 0; k < 4; ++k) {
            int m = d - 3 + k;
            if ((unsigned)m < 8u) Fc[m] = ((const float*)&vv)[k];
        }
    }
    // full cpad cubic-coefficient table into own LDS (4 items/thread)
#pragma unroll
    for (int e = tid; e < CH * 16; e += 256) {
        int c = e >> 4, dd = e & 15;
        float4 cf = make_float4(0.f, 0.f, 0.f, 0.f);
        if (dd <= 10) {
            float sc = fwsc[c];
            float w0 = 0.f, w1 = 0.f, w2 = 0.f, w3 = 0.f;
            int m0 = dd - 3;
            if ((unsigned)(m0 + 0) < 8u) w0 = fws[c * GK + m0 + 0] * sc;
            if ((unsigned)(m0 + 1) < 8u) w1 = fws[c * GK + m0 + 1] * sc;
            if ((unsigned)(m0 + 2) < 8u) w2 = fws[c * GK + m0 + 2] * sc;
            if ((unsigned)(m0 + 3) < 8u) w3 = fws[c * GK + m0 + 3] * sc;
            cf.x = (w0 + 4.0f * w1 + w2) * (1.0f / 6.0f);
            cf.y = (w2 - w0) * 0.5f;
            cf.z = (w0 - 2.0f * w1 + w2) * 0.5f;
            cf.w = (w3 - w0 + 3.0f * (w1 - w2)) * (1.0f / 6.0f);
        }
        cpad[c][dd] = cf;
    }
    if (tid < 16) {
        xi4[tid] = ((const float4*)(x + (b * NB + i) * CH))[tid];
    } else if (tid < 32) {
        fb4[tid - 16] = ((const float4*)fwb)[tid - 16];
    }
    // W2U fold slice: 36 float4/block, 512 blocks cover 288*64 = 18432
    if (tid < 36) {
        int item = r * 36 + tid;
        int k4 = item >> 6, o = item & 63;
        float4 v;
#pragma unroll
        for (int kk = 0; kk < 4; ++kk) {
            int k = k4 * 4 + kk, c = k / 9, g = k - c * 9;
            ((float*)&v)[kk] = (g < 8)
                ? uws[(o * UIN + c) * GK + g] * uwsc[o * UIN + c]
                : uwb[o * UIN + c];
        }
        ((float4*)(ws + WS_W2U))[item] = v;
    }
    __syncthreads();

    // msg matvec with inline fold: lane o streams its contiguous raw
    // weight row; acc = sum_c sc[o,c]*(mws[o,c,:].F[c,:]) + mwb[o,c]*silu
    {
        const int o = tid & 63, cw = tid >> 6, c0 = cw * 16;
        const float4* mws4 = (const float4*)mws;
        float acc = 0.0f;
#pragma unroll
        for (int gq = 0; gq < 4; ++gq) {
            int c = c0 + gq * 4;
            float4 scv = *(const float4*)(mwsc + o * CH + c);
            float4 bbv = *(const float4*)(mwb + o * CH + c);
#pragma unroll
            for (int q = 0; q < 4; ++q) {
                int cc = c + q;
                float4 w0 = mws4[(o * CH + cc) * 2];
                float4 w1 = mws4[(o * CH + cc) * 2 + 1];
                const float* Fc = F2 + cc * 16;
                float4 f0 = *(const float4*)Fc;       // uniform broadcast
                float4 f1 = *(const float4*)(Fc + 4);
                float dot = w0.x * f0.x + w0.y * f0.y + w0.z * f0.z
                          + w0.w * f0.w + w1.x * f1.x + w1.y * f1.y
                          + w1.z * f1.z + w1.w * f1.w;
                acc = fmaf(((const float*)&scv)[q], dot, acc);
                acc = fmaf(((const float*)&bbv)[q], Fc[8], acc);
            }
        }
        pmsg[cw * 64 + o] = acc;
    }
    __syncthreads();
    if (tid < OUTF)
        ws[WS_MSG + r * OUTF + tid] =
            pmsg[tid] + pmsg[64 + tid] + pmsg[128 + tid] + pmsg[192 + tid];

    // ---- issue phase-B global loads now; latency hides under barrier ----
    float4 xj[16];
    {
        const float4* xrow = (const float4*)(x + (b * NB + tid) * CH);
#pragma unroll
        for (int c4 = 0; c4 < 16; ++c4) xj[c4] = xrow[c4];
    }
    int adjv = adj[(b * NB + i) * NB + tid];

    // ================= DEVICE BARRIER =================
    __syncthreads();   // compiler drains vmcnt before s_barrier: msg in L2
    if (tid == 0) {
        int ep = __hip_atomic_load(&g_epoch, __ATOMIC_RELAXED,
                                   __HIP_MEMORY_SCOPE_AGENT);
        int k = (r & 7) * 32;
        int gsz = (int)(gridDim.x >> 3);
        int prev = __hip_atomic_fetch_add(&g_cnt[k], 1, __ATOMIC_ACQ_REL,
                                          __HIP_MEMORY_SCOPE_AGENT);
        bool released = false;
        if (prev == gsz - 1) {                    // last in my group
            __hip_atomic_store(&g_cnt[k], 0, __ATOMIC_RELAXED,
                               __HIP_MEMORY_SCOPE_AGENT);
            int p2v = __hip_atomic_fetch_add(&g_sub, 1, __ATOMIC_ACQ_REL,
                                             __HIP_MEMORY_SCOPE_AGENT);
            if (p2v == 7) {                       // last group overall
                __hip_atomic_store(&g_sub, 0, __ATOMIC_RELAXED,
                                   __HIP_MEMORY_SCOPE_AGENT);
                __hip_atomic_store(&g_epoch, ep + 1, __ATOMIC_RELEASE,
                                   __HIP_MEMORY_SCOPE_AGENT);
                released = true;
            }
        }
        if (!released) {
            // bounded spin: residency failure -> wrong result, not a hang
            for (int it = 0; it < (1 << 20); ++it) {
                if (__hip_atomic_load(&g_epoch, __ATOMIC_ACQUIRE,
                                      __HIP_MEMORY_SCOPE_AGENT) != ep) break;
                __builtin_amdgcn_s_sleep(16);
            }
        }
    }
    __syncthreads();
    __threadfence();   // device-scope acquire for all lanes

    // ================= PHASE B (gat row r) =================
    if (tid < 16) ((float4*)comb)[tid] = xi4[tid];

    // energy(i, j=tid): x-row in registers + LDS b128 coef gather
    float e0 = 0.0f;
#pragma unroll
    for (int c4 = 0; c4 < 16; ++c4) {
        float4 xiv = xi4[c4];
        float4 fbv = fb4[c4];
        float4 xjv = xj[c4];
#pragma unroll
        for (int q = 0; q < 4; ++q) {
            float rr = ((const float*)&xiv)[q] - ((const float*)&xjv)[q];
            float pp = fmaf(rr, 2.5f, 5.5f);
            float fd = floorf(pp);
            int d = (int)fd;
            float u = pp - fd;
            if ((unsigned)d > 10u) d = 11;
            float4 cf = cpad[c4 * 4 + q][d];   // b128 gather, <=2-way
            float t = fmaf(u, cf.w, cf.z);
            t = fmaf(u, t, cf.y);
            t = fmaf(u, t, cf.x);
            e0 += fmaf(silu(rr), ((const float*)&fbv)[q], t);
        }
    }
    if (adjv == 0) e0 = -1e9f;

    // softmax over j
    float mx = e0;
#pragma unroll
    for (int off = 32; off > 0; off >>= 1)
        mx = fmaxf(mx, __shfl_xor(mx, off, 64));
    if ((tid & 63) == 0) wred[tid >> 6] = mx;
    __syncthreads();
    mx = fmaxf(fmaxf(wred[0], wred[1]), fmaxf(wred[2], wred[3]));
    float pexp = __expf(e0 - mx);
    float sw = pexp;
#pragma unroll
    for (int off = 32; off > 0; off >>= 1)
        sw += __shfl_xor(sw, off, 64);
    __syncthreads();
    if ((tid & 63) == 0) wred[tid >> 6] = sw;
    __syncthreads();
    float denom = wred[0] + wred[1] + wred[2] + wred[3];
    alpha[tid] = pexp * __builtin_amdgcn_rcpf(denom);
    __syncthreads();

    // aggr[o] = sum_j alpha[j]*msg[b,j,o], float4 over o
    {
        const int o4 = tid & 15, seg = tid >> 4;
        const float4* msgb4 =
            (const float4*)(ws + WS_MSG + (b * NB + seg * 16) * OUTF);
        float4 a = make_float4(0.f, 0.f, 0.f, 0.f);
#pragma unroll
        for (int jj = 0; jj < 16; ++jj) {
            float al = alpha[seg * 16 + jj];
            float4 mv = msgb4[jj * 16 + o4];       // coalesced b128
            a.x = fmaf(al, mv.x, a.x);
            a.y = fmaf(al, mv.y, a.y);
            a.z = fmaf(al, mv.z, a.z);
            a.w = fmaf(al, mv.w, a.w);
        }
        part4[seg * 16 + o4] = a;
    }
    __syncthreads();
    if (tid < OUTF) {
        const float* p = (const float*)part4;
        float s = 0.0f;
#pragma unroll
        for (int sg = 0; sg < 16; ++sg) s += p[sg * 64 + tid];  // conflict-free
        comb[CH + tid] = s;
    }
    __syncthreads();

    // update-KAN features (128 channels -> 1152 LDS rows)
    if (tid < UIN) {
        float v = comb[tid];
#pragma unroll
        for (int g = 0; g < 8; ++g) Fu[tid * 9 + g] = 0.0f;
        Fu[tid * 9 + 8] = silu(v);
        int d; float4 vv; spline4(v, d, vv);
#pragma unroll
        for (int k = 0; k < 4; ++k) {
            int m = d - 3 + k;
            if ((unsigned)m < 8u) Fu[tid * 9 + m] = ((const float*)&vv)[k];
        }
    }
    __syncthreads();

    // update matvec: 4 waves x 72 float4-k iters, coalesced W
    {
        const int o = tid & 63, w = tid >> 6;
        const float4* W = (const float4*)(ws + WS_W2U);
        const float4* Fv = (const float4*)Fu;
        float acc = 0.0f;
#pragma unroll 4
        for (int k4 = w * 72; k4 < w * 72 + 72; ++k4) {
            float4 f = Fv[k4];
            float4 wt = W[k4 * 64 + o];
            acc += f.x * wt.x + f.y * wt.y + f.z * wt.z + f.w * wt.w;
        }
        p2[w * 64 + o] = acc;
    }
    __syncthreads();
    if (tid < OUTF)
        out[r * OUTF + tid] =
            p2[tid] + p2[64 + tid] + p2[128 + tid] + p2[192 + tid];
}

extern "C" void kernel_launch(void* const* d_in, const int* in_sizes, int n_in,
                              void* d_out, int out_size, void* d_ws, size_t ws_size,
                              hipStream_t stream) {
    const float* x     = (const float*)d_in[0];
    const int*   adj   = (const int*)d_in[1];
    const float* fwb   = (const float*)d_in[2];
    const float* fws   = (const float*)d_in[3];
    const float* fwsc  = (const float*)d_in[4];
    const float* mwb   = (const float*)d_in[5];
    const float* mws   = (const float*)d_in[6];
    const float* mwsc  = (const float*)d_in[7];
    const float* uwb   = (const float*)d_in[8];
    const float* uws   = (const float*)d_in[9];
    const float* uwsc  = (const float*)d_in[10];
    float* out = (float*)d_out;
    float* ws = (float*)d_ws;

    const int BN = in_sizes[0] / CH;   // 512 = 2 batches x 256 rows

    fused_kernel<<<BN, 256, 0, stream>>>(x, adj, fwb, fws, fwsc,
                                         mwb, mws, mwsc, uwb, uws, uwsc,
                                         ws, out);
}

// Round 5
// 105.405 us; speedup vs baseline: 1.7645x; 1.7645x over previous
//
#include <hip/hip_runtime.h>
#include <math.h>

#define NB 256     // N nodes
#define CH 64      // C input features
#define OUTF 64    // O output features
#define GK 8       // GRID_SIZE + SPLINE_ORDER
#define UIN 128    // update-KAN input dim (C + O)
#define KU (UIN * 9)   // 1152 feature rows for update KAN
#define KU4 (KU / 4)   // 288

// workspace layout in floats
#define WS_MSG 0          // 512*64   = 32768
#define WS_W2U 32768      // 288*64*4 = 73728
#define WS_CPAD 106496    // 64*16*4  = 4096
// total 110592 floats = 432 KB

__device__ __forceinline__ float silu(float v) {
    return v * __builtin_amdgcn_rcpf(1.0f + __expf(-v));
}

// Uniform cubic B-spline, knots t(m)=0.4m-2.2. Interval d=floor((r+2.2)*2.5),
// u=frac. 4 nonzero bases m=d-3..d. Out of grid -> d=11 (zeros).
__device__ __forceinline__ void spline4(float r, int& d, float4& v) {
    float p = fmaf(r, 2.5f, 5.5f);   // (r+2.2)*2.5
    float fd = floorf(p);
    d = (int)fd;
    float u = p - fd;
    if ((unsigned)d > 10u) d = 11;
    float um = 1.0f - u;
    float u2 = u * u, u3 = u2 * u;
    const float k6 = 1.0f / 6.0f;
    v.x = um * um * um * k6;
    v.y = (3.0f * u3 - 6.0f * u2 + 4.0f) * k6;
    v.z = (-3.0f * u3 + 3.0f * u2 + 3.0f * u + 1.0f) * k6;
    v.w = u3 * k6;
}

// Launch 1: msg row per block (inline weight fold — no W2m table needed),
// plus cooperative prep of the W2U fold (36 float4/block) and the cpad
// cubic-coefficient table (2 float4/block). Launch boundary = barrier.
__global__ __launch_bounds__(256) void msg_kernel(
    const float* __restrict__ x,
    const float* __restrict__ mwb, const float* __restrict__ mws,
    const float* __restrict__ mwsc,
    const float* __restrict__ uwb, const float* __restrict__ uws,
    const float* __restrict__ uwsc,
    const float* __restrict__ fws, const float* __restrict__ fwsc,
    float* __restrict__ ws) {
    const int r = blockIdx.x, tid = threadIdx.x;
    __shared__ __align__(16) float F2[CH * 16];  // [c][0..7]=spline,[8]=silu
    __shared__ float pmsg[4][OUTF];

    if (tid < CH) {
        float v = x[r * CH + tid];
        float* Fc = F2 + tid * 16;
#pragma unroll
        for (int g = 0; g < 8; ++g) Fc[g] = 0.0f;
        Fc[8] = silu(v);
        int d; float4 vv; spline4(v, d, vv);
#pragma unroll
        for (int k = 0; k < 4; ++k) {
            int m = d - 3 + k;
            if ((unsigned)m < 8u) Fc[m] = ((const float*)&vv)[k];
        }
    }
    // W2U fold slice: 36 float4/block, 512 blocks cover 288*64 = 18432
    if (tid >= 64 && tid < 100) {
        int item = r * 36 + (tid - 64);
        int k4 = item >> 6, o = item & 63;
        float4 v;
#pragma unroll
        for (int kk = 0; kk < 4; ++kk) {
            int k = k4 * 4 + kk, c = k / 9, g = k - c * 9;
            ((float*)&v)[kk] = (g < 8)
                ? uws[(o * UIN + c) * GK + g] * uwsc[o * UIN + c]
                : uwb[o * UIN + c];
        }
        ((float4*)(ws + WS_W2U))[item] = v;
    }
    // cpad slice: 2 float4/block, 512 blocks cover 64*16 = 1024
    if (tid >= 100 && tid < 102) {
        int e = r * 2 + (tid - 100);
        int c = e >> 4, dd = e & 15;
        float4 cf = make_float4(0.f, 0.f, 0.f, 0.f);
        if (dd <= 10) {
            float sc = fwsc[c];
            float w0 = 0.f, w1 = 0.f, w2 = 0.f, w3 = 0.f;
            int m0 = dd - 3;
            if ((unsigned)(m0 + 0) < 8u) w0 = fws[c * GK + m0 + 0] * sc;
            if ((unsigned)(m0 + 1) < 8u) w1 = fws[c * GK + m0 + 1] * sc;
            if ((unsigned)(m0 + 2) < 8u) w2 = fws[c * GK + m0 + 2] * sc;
            if ((unsigned)(m0 + 3) < 8u) w3 = fws[c * GK + m0 + 3] * sc;
            cf.x = (w0 + 4.0f * w1 + w2) * (1.0f / 6.0f);
            cf.y = (w2 - w0) * 0.5f;
            cf.z = (w0 - 2.0f * w1 + w2) * 0.5f;
            cf.w = (w3 - w0 + 3.0f * (w1 - w2)) * (1.0f / 6.0f);
        }
        ((float4*)(ws + WS_CPAD))[e] = cf;
    }
    __syncthreads();

    // msg matvec with inline fold: lane o streams its contiguous raw
    // weight rows; acc = sum_c sc[o,c]*(mws[o,c,:].F[c,:]) + mwb[o,c]*silu
    {
        const int o = tid & 63, cw = tid >> 6, c0 = cw * 16;
        const float4* mws4 = (const float4*)mws;
        float acc = 0.0f;
#pragma unroll
        for (int gq = 0; gq < 4; ++gq) {
            int c = c0 + gq * 4;
            float4 scv = *(const float4*)(mwsc + o * CH + c);
            float4 bbv = *(const float4*)(mwb + o * CH + c);
#pragma unroll
            for (int q = 0; q < 4; ++q) {
                int cc = c + q;
                float4 w0 = mws4[(o * CH + cc) * 2];
                float4 w1 = mws4[(o * CH + cc) * 2 + 1];
                const float* Fc = F2 + cc * 16;
                float4 f0 = *(const float4*)Fc;       // uniform broadcast
                float4 f1 = *(const float4*)(Fc + 4);
                float dot = w0.x * f0.x + w0.y * f0.y + w0.z * f0.z
                          + w0.w * f0.w + w1.x * f1.x + w1.y * f1.y
                          + w1.z * f1.z + w1.w * f1.w;
                acc = fmaf(((const float*)&scv)[q], dot, acc);
                acc = fmaf(((const float*)&bbv)[q], Fc[8], acc);
            }
        }
        pmsg[cw][o] = acc;
    }
    __syncthreads();
    if (tid < OUTF)
        ws[WS_MSG + r * OUTF + tid] =
            pmsg[0][tid] + pmsg[1][tid] + pmsg[2][tid] + pmsg[3][tid];
}

// Launch 2: one block per (b,i): energy -> softmax -> aggregate -> update KAN.
__global__ __launch_bounds__(256, 2) void gat_kernel(
    const float* __restrict__ x,     // (B, N, C)
    const int* __restrict__ adj,
    const float* __restrict__ fwb,
    const float* __restrict__ cpadg, // (CH*16) float4 from launch 1
    const float* __restrict__ w2u,   // (KU4*64) float4
    const float* __restrict__ msg,   // (B, N, O)
    float* __restrict__ out) {
    const int b = blockIdx.x >> 8;
    const int i = blockIdx.x & 255;
    const int tid = threadIdx.x;     // == j in energy phase

    __shared__ float4 cpad[CH][16];  // per-interval cubic coefs (zero-padded)
    __shared__ float4 xi4[16];       // x_i row as float4
    __shared__ float4 fb4[16];       // fwb as float4
    __shared__ float alpha[NB];
    __shared__ float comb[UIN];
    __shared__ __align__(16) float Fu[KU];
    __shared__ float4 part4[16][16]; // aggr partials: 16 segs x 64 floats
    __shared__ float part[4][OUTF];  // matvec partials
    __shared__ float wred[4];

    // Register-preload this thread's j-row of x (j = tid); latency hides
    // under the LDS setup below.
    float4 xj[16];
    {
        const float4* xrow = (const float4*)(x + (b * NB + tid) * CH);
#pragma unroll
        for (int c4 = 0; c4 < 16; ++c4) xj[c4] = xrow[c4];
    }

    if (tid < 16) {
        float4 v = ((const float4*)(x + (b * NB + i) * CH))[tid];
        xi4[tid] = v;
        ((float4*)comb)[tid] = v;
    } else if (tid < 32) {
        fb4[tid - 16] = ((const float4*)fwb)[tid - 16];
    }
    // load precomputed cpad: 1024 float4, coalesced
    {
        const float4* cp = (const float4*)cpadg;
        float4* cds = (float4*)cpad;
#pragma unroll
        for (int k = 0; k < 4; ++k) cds[tid + k * 256] = cp[tid + k * 256];
    }
    __syncthreads();

    // ---- energy(i, j=tid): x-row in registers + LDS b128 coef gather ----
    float e = 0.0f;
#pragma unroll
    for (int c4 = 0; c4 < 16; ++c4) {
        float4 xiv = xi4[c4];              // uniform b128 broadcast
        float4 fbv = fb4[c4];
        float4 xjv = xj[c4];               // registers
#pragma unroll
        for (int q = 0; q < 4; ++q) {
            float r = ((const float*)&xiv)[q] - ((const float*)&xjv)[q];
            float pp = fmaf(r, 2.5f, 5.5f);
            float fd = floorf(pp);
            int d = (int)fd;
            float u = pp - fd;
            if ((unsigned)d > 10u) d = 11;
            float4 cf = cpad[c4 * 4 + q][d];   // b128 gather, <=2-way
            float t = fmaf(u, cf.w, cf.z);
            t = fmaf(u, t, cf.y);
            t = fmaf(u, t, cf.x);
            e += fmaf(silu(r), ((const float*)&fbv)[q], t);
        }
    }
    if (adj[(b * NB + i) * NB + tid] == 0) e = -1e9f;

    // ---- softmax over j ----
    float mx = e;
#pragma unroll
    for (int off = 32; off > 0; off >>= 1)
        mx = fmaxf(mx, __shfl_xor(mx, off, 64));
    if ((tid & 63) == 0) wred[tid >> 6] = mx;
    __syncthreads();
    mx = fmaxf(fmaxf(wred[0], wred[1]), fmaxf(wred[2], wred[3]));
    float pexp = __expf(e - mx);
    float sw = pexp;
#pragma unroll
    for (int off = 32; off > 0; off >>= 1)
        sw += __shfl_xor(sw, off, 64);
    __syncthreads();
    if ((tid & 63) == 0) wred[tid >> 6] = sw;
    __syncthreads();
    float denom = wred[0] + wred[1] + wred[2] + wred[3];
    alpha[tid] = pexp * __builtin_amdgcn_rcpf(denom);
    __syncthreads();

    // ---- aggr[o] = sum_j alpha[j]*msg[b,j,o], float4 over o ----
    {
        const int o4 = tid & 15, seg = tid >> 4;   // 16 segs x 16 j each
        const float4* msgb4 = (const float4*)(msg + (b * NB + seg * 16) * OUTF);
        float4 a = make_float4(0.f, 0.f, 0.f, 0.f);
#pragma unroll
        for (int jj = 0; jj < 16; ++jj) {
            float al = alpha[seg * 16 + jj];
            float4 mv = msgb4[jj * 16 + o4];       // coalesced b128
            a.x = fmaf(al, mv.x, a.x);
            a.y = fmaf(al, mv.y, a.y);
            a.z = fmaf(al, mv.z, a.z);
            a.w = fmaf(al, mv.w, a.w);
        }
        part4[seg][o4] = a;
    }
    __syncthreads();
    if (tid < OUTF) {
        const float* p = (const float*)part4;
        float s = 0.0f;
#pragma unroll
        for (int sg = 0; sg < 16; ++sg) s += p[sg * 64 + tid];  // conflict-free
        comb[CH + tid] = s;
    }
    __syncthreads();

    // ---- update-KAN features (128 channels -> 1152 LDS rows) ----
    if (tid < UIN) {
        float v = comb[tid];
#pragma unroll
        for (int g = 0; g < 8; ++g) Fu[tid * 9 + g] = 0.0f;
        Fu[tid * 9 + 8] = silu(v);
        int d; float4 vv; spline4(v, d, vv);
#pragma unroll
        for (int k = 0; k < 4; ++k) {
            int m = d - 3 + k;
            if ((unsigned)m < 8u) Fu[tid * 9 + m] = ((const float*)&vv)[k];
        }
    }
    __syncthreads();

    // ---- update matvec: 4 waves x 72 float4-k iters, coalesced W ----
    {
        const int o = tid & 63, w = tid >> 6;
        const float4* W = (const float4*)w2u;
        const float4* Fv = (const float4*)Fu;
        float acc = 0.0f;
#pragma unroll 4
        for (int k4 = w * 72; k4 < w * 72 + 72; ++k4) {
            float4 f = Fv[k4];
            float4 wt = W[k4 * 64 + o];
            acc += f.x * wt.x + f.y * wt.y + f.z * wt.z + f.w * wt.w;
        }
        part[w][o] = acc;
    }
    __syncthreads();
    if (tid < OUTF)
        out[(b * NB + i) * OUTF + tid] =
            part[0][tid] + part[1][tid] + part[2][tid] + part[3][tid];
}

extern "C" void kernel_launch(void* const* d_in, const int* in_sizes, int n_in,
                              void* d_out, int out_size, void* d_ws, size_t ws_size,
                              hipStream_t stream) {
    const float* x     = (const float*)d_in[0];
    const int*   adj   = (const int*)d_in[1];
    const float* fwb   = (const float*)d_in[2];
    const float* fws   = (const float*)d_in[3];
    const float* fwsc  = (const float*)d_in[4];
    const float* mwb   = (const float*)d_in[5];
    const float* mws   = (const float*)d_in[6];
    const float* mwsc  = (const float*)d_in[7];
    const float* uwb   = (const float*)d_in[8];
    const float* uws   = (const float*)d_in[9];
    const float* uwsc  = (const float*)d_in[10];
    float* out = (float*)d_out;
    float* ws = (float*)d_ws;

    const int BN = in_sizes[0] / CH;   // 512 = 2 batches x 256 rows

    msg_kernel<<<BN, 256, 0, stream>>>(x, mwb, mws, mwsc, uwb, uws, uwsc,
                                       fws, fwsc, ws);
    gat_kernel<<<BN, 256, 0, stream>>>(x, adj, fwb, ws + WS_CPAD,
                                       ws + WS_W2U, ws + WS_MSG, out);
}

// Round 6
// 99.348 us; speedup vs baseline: 1.8720x; 1.0610x over previous
//
#include <hip/hip_runtime.h>
#include <math.h>

#define NB 256     // N nodes
#define CH 64      // C input features
#define OUTF 64    // O output features
#define GK 8       // GRID_SIZE + SPLINE_ORDER
#define UIN 128    // update-KAN input dim (C + O)
#define KU (UIN * 9)   // 1152 feature rows for update KAN
#define KU4 (KU / 4)   // 288

// workspace layout in floats
#define WS_MSG 0          // 512*64   = 32768
#define WS_W2U 32768      // 288*64*4 = 73728
#define WS_CPAD 106496    // 64*16*4  = 4096
// total 110592 floats = 432 KB

__device__ __forceinline__ float silu(float v) {
    return v * __builtin_amdgcn_rcpf(1.0f + __expf(-v));
}

// Uniform cubic B-spline, knots t(m)=0.4m-2.2. Interval d=floor((r+2.2)*2.5),
// u=frac. 4 nonzero bases m=d-3..d. Out of grid -> d=11 (zeros).
__device__ __forceinline__ void spline4(float r, int& d, float4& v) {
    float p = fmaf(r, 2.5f, 5.5f);   // (r+2.2)*2.5
    float fd = floorf(p);
    d = (int)fd;
    float u = p - fd;
    if ((unsigned)d > 10u) d = 11;
    float um = 1.0f - u;
    float u2 = u * u, u3 = u2 * u;
    const float k6 = 1.0f / 6.0f;
    v.x = um * um * um * k6;
    v.y = (3.0f * u3 - 6.0f * u2 + 4.0f) * k6;
    v.z = (-3.0f * u3 + 3.0f * u2 + 3.0f * u + 1.0f) * k6;
    v.w = u3 * k6;
}

// Launch 1: msg row per block with COALESCED inline fold (lane = channel,
// wave = 16 outputs; mws read as contiguous 2KB rows), plus cooperative
// prep of W2U fold (36 float4/block) and cpad table (2 float4/block).
__global__ __launch_bounds__(256) void msg_kernel(
    const float* __restrict__ x,
    const float* __restrict__ mwb, const float* __restrict__ mws,
    const float* __restrict__ mwsc,
    const float* __restrict__ uwb, const float* __restrict__ uws,
    const float* __restrict__ uwsc,
    const float* __restrict__ fws, const float* __restrict__ fwsc,
    float* __restrict__ ws) {
    const int r = blockIdx.x, tid = threadIdx.x;
    __shared__ __align__(16) float F2[CH * 16];  // [c][0..7]=spline,[8]=silu

    if (tid < CH) {
        float v = x[r * CH + tid];
        float* Fc = F2 + tid * 16;
#pragma unroll
        for (int g = 0; g < 8; ++g) Fc[g] = 0.0f;
        Fc[8] = silu(v);
        int d; float4 vv; spline4(v, d, vv);
#pragma unroll
        for (int k = 0; k < 4; ++k) {
            int m = d - 3 + k;
            if ((unsigned)m < 8u) Fc[m] = ((const float*)&vv)[k];
        }
    }
    // W2U fold slice: 36 float4/block, 512 blocks cover 288*64 = 18432
    if (tid >= 64 && tid < 100) {
        int item = r * 36 + (tid - 64);
        int k4 = item >> 6, o = item & 63;
        float4 v;
#pragma unroll
        for (int kk = 0; kk < 4; ++kk) {
            int k = k4 * 4 + kk, c = k / 9, g = k - c * 9;
            ((float*)&v)[kk] = (g < 8)
                ? uws[(o * UIN + c) * GK + g] * uwsc[o * UIN + c]
                : uwb[o * UIN + c];
        }
        ((float4*)(ws + WS_W2U))[item] = v;
    }
    // cpad slice: 2 float4/block, 512 blocks cover 64*16 = 1024
    if (tid >= 100 && tid < 102) {
        int e = r * 2 + (tid - 100);
        int c = e >> 4, dd = e & 15;
        float4 cf = make_float4(0.f, 0.f, 0.f, 0.f);
        if (dd <= 10) {
            float sc = fwsc[c];
            float w0 = 0.f, w1 = 0.f, w2 = 0.f, w3 = 0.f;
            int m0 = dd - 3;
            if ((unsigned)(m0 + 0) < 8u) w0 = fws[c * GK + m0 + 0] * sc;
            if ((unsigned)(m0 + 1) < 8u) w1 = fws[c * GK + m0 + 1] * sc;
            if ((unsigned)(m0 + 2) < 8u) w2 = fws[c * GK + m0 + 2] * sc;
            if ((unsigned)(m0 + 3) < 8u) w3 = fws[c * GK + m0 + 3] * sc;
            cf.x = (w0 + 4.0f * w1 + w2) * (1.0f / 6.0f);
            cf.y = (w2 - w0) * 0.5f;
            cf.z = (w0 - 2.0f * w1 + w2) * 0.5f;
            cf.w = (w3 - w0 + 3.0f * (w1 - w2)) * (1.0f / 6.0f);
        }
        ((float4*)(ws + WS_CPAD))[e] = cf;
    }
    __syncthreads();

    // Coalesced fold matvec: lane c owns channel c; wave w owns outputs
    // o = w*16..w*16+15. Per o: mws row read as contiguous 2KB across the
    // wave; per-lane contribution sc*dot + mwb*silu; butterfly-reduce.
    {
        const int lane = tid & 63, w = tid >> 6;
        const float* Fc = F2 + lane * 16;
        float4 f0 = *(const float4*)Fc;        // one-time LDS reads
        float4 f1 = *(const float4*)(Fc + 4);
        float sl = Fc[8];
        float acc[16];
#pragma unroll
        for (int oo = 0; oo < 16; ++oo) {
            int o = w * 16 + oo;
            const float4* w4 = (const float4*)(mws + (o * CH + lane) * GK);
            float4 w0 = w4[0];                 // lanes 32B apart: coalesced
            float4 w1 = w4[1];
            float sc = mwsc[o * CH + lane];    // coalesced dword
            float bb = mwb[o * CH + lane];
            float dot = w0.x * f0.x + w0.y * f0.y + w0.z * f0.z + w0.w * f0.w
                      + w1.x * f1.x + w1.y * f1.y + w1.z * f1.z + w1.w * f1.w;
            acc[oo] = fmaf(sc, dot, bb * sl);
        }
#pragma unroll
        for (int oo = 0; oo < 16; ++oo) {
            float a = acc[oo];
#pragma unroll
            for (int off = 32; off > 0; off >>= 1)
                a += __shfl_xor(a, off, 64);
            acc[oo] = a;                       // all lanes hold full sum
        }
        if (lane == 0) {
            float* mrow = ws + WS_MSG + r * OUTF + w * 16;
#pragma unroll
            for (int oo = 0; oo < 16; ++oo) mrow[oo] = acc[oo];  // static idx
        }
    }
}

// Launch 2: one block per (b,i): energy -> softmax -> aggregate -> update KAN.
__global__ __launch_bounds__(256, 2) void gat_kernel(
    const float* __restrict__ x,     // (B, N, C)
    const int* __restrict__ adj,
    const float* __restrict__ fwb,
    const float* __restrict__ cpadg, // (CH*16) float4 from launch 1
    const float* __restrict__ w2u,   // (KU4*64) float4
    const float* __restrict__ msg,   // (B, N, O)
    float* __restrict__ out) {
    const int b = blockIdx.x >> 8;
    const int i = blockIdx.x & 255;
    const int tid = threadIdx.x;     // == j in energy phase

    __shared__ float4 cpad[CH][16];  // per-interval cubic coefs (zero-padded)
    __shared__ float4 xi4[16];       // x_i row as float4
    __shared__ float4 fb4[16];       // fwb as float4
    __shared__ float alpha[NB];
    __shared__ float comb[UIN];
    __shared__ __align__(16) float Fu[KU];
    __shared__ float4 part4[16][16]; // aggr partials: 16 segs x 64 floats
    __shared__ float part[4][OUTF];  // matvec partials
    __shared__ float wred[4];

    // Register-preload this thread's j-row of x (j = tid); latency hides
    // under the LDS setup below.
    float4 xj[16];
    {
        const float4* xrow = (const float4*)(x + (b * NB + tid) * CH);
#pragma unroll
        for (int c4 = 0; c4 < 16; ++c4) xj[c4] = xrow[c4];
    }

    if (tid < 16) {
        float4 v = ((const float4*)(x + (b * NB + i) * CH))[tid];
        xi4[tid] = v;
        ((float4*)comb)[tid] = v;
    } else if (tid < 32) {
        fb4[tid - 16] = ((const float4*)fwb)[tid - 16];
    }
    // load precomputed cpad: 1024 float4, coalesced
    {
        const float4* cp = (const float4*)cpadg;
        float4* cds = (float4*)cpad;
#pragma unroll
        for (int k = 0; k < 4; ++k) cds[tid + k * 256] = cp[tid + k * 256];
    }
    __syncthreads();

    // ---- energy(i, j=tid): x-row in registers + LDS b128 coef gather ----
    float e = 0.0f;
#pragma unroll
    for (int c4 = 0; c4 < 16; ++c4) {
        float4 xiv = xi4[c4];              // uniform b128 broadcast
        float4 fbv = fb4[c4];
        float4 xjv = xj[c4];               // registers
#pragma unroll
        for (int q = 0; q < 4; ++q) {
            float r = ((const float*)&xiv)[q] - ((const float*)&xjv)[q];
            float pp = fmaf(r, 2.5f, 5.5f);
            float fd = floorf(pp);
            int d = (int)fd;
            float u = pp - fd;
            if ((unsigned)d > 10u) d = 11;
            float4 cf = cpad[c4 * 4 + q][d];   // b128 gather, <=2-way
            float t = fmaf(u, cf.w, cf.z);
            t = fmaf(u, t, cf.y);
            t = fmaf(u, t, cf.x);
            e += fmaf(silu(r), ((const float*)&fbv)[q], t);
        }
    }
    if (adj[(b * NB + i) * NB + tid] == 0) e = -1e9f;

    // ---- softmax over j ----
    float mx = e;
#pragma unroll
    for (int off = 32; off > 0; off >>= 1)
        mx = fmaxf(mx, __shfl_xor(mx, off, 64));
    if ((tid & 63) == 0) wred[tid >> 6] = mx;
    __syncthreads();
    mx = fmaxf(fmaxf(wred[0], wred[1]), fmaxf(wred[2], wred[3]));
    float pexp = __expf(e - mx);
    float sw = pexp;
#pragma unroll
    for (int off = 32; off > 0; off >>= 1)
        sw += __shfl_xor(sw, off, 64);
    __syncthreads();
    if ((tid & 63) == 0) wred[tid >> 6] = sw;
    __syncthreads();
    float denom = wred[0] + wred[1] + wred[2] + wred[3];
    alpha[tid] = pexp * __builtin_amdgcn_rcpf(denom);
    __syncthreads();

    // ---- aggr[o] = sum_j alpha[j]*msg[b,j,o], float4 over o ----
    {
        const int o4 = tid & 15, seg = tid >> 4;   // 16 segs x 16 j each
        const float4* msgb4 = (const float4*)(msg + (b * NB + seg * 16) * OUTF);
        float4 a = make_float4(0.f, 0.f, 0.f, 0.f);
#pragma unroll
        for (int jj = 0; jj < 16; ++jj) {
            float al = alpha[seg * 16 + jj];
            float4 mv = msgb4[jj * 16 + o4];       // coalesced b128
            a.x = fmaf(al, mv.x, a.x);
            a.y = fmaf(al, mv.y, a.y);
            a.z = fmaf(al, mv.z, a.z);
            a.w = fmaf(al, mv.w, a.w);
        }
        part4[seg][o4] = a;
    }
    __syncthreads();
    if (tid < OUTF) {
        const float* p = (const float*)part4;
        float s = 0.0f;
#pragma unroll
        for (int sg = 0; sg < 16; ++sg) s += p[sg * 64 + tid];  // conflict-free
        comb[CH + tid] = s;
    }
    __syncthreads();

    // ---- update-KAN features (128 channels -> 1152 LDS rows) ----
    if (tid < UIN) {
        float v = comb[tid];
#pragma unroll
        for (int g = 0; g < 8; ++g) Fu[tid * 9 + g] = 0.0f;
        Fu[tid * 9 + 8] = silu(v);
        int d; float4 vv; spline4(v, d, vv);
#pragma unroll
        for (int k = 0; k < 4; ++k) {
            int m = d - 3 + k;
            if ((unsigned)m < 8u) Fu[tid * 9 + m] = ((const float*)&vv)[k];
        }
    }
    __syncthreads();

    // ---- update matvec: 4 waves x 72 float4-k iters, coalesced W ----
    {
        const int o = tid & 63, w = tid >> 6;
        const float4* W = (const float4*)w2u;
        const float4* Fv = (const float4*)Fu;
        float acc = 0.0f;
#pragma unroll 4
        for (int k4 = w * 72; k4 < w * 72 + 72; ++k4) {
            float4 f = Fv[k4];
            float4 wt = W[k4 * 64 + o];
            acc += f.x * wt.x + f.y * wt.y + f.z * wt.z + f.w * wt.w;
        }
        part[w][o] = acc;
    }
    __syncthreads();
    if (tid < OUTF)
        out[(b * NB + i) * OUTF + tid] =
            part[0][tid] + part[1][tid] + part[2][tid] + part[3][tid];
}

extern "C" void kernel_launch(void* const* d_in, const int* in_sizes, int n_in,
                              void* d_out, int out_size, void* d_ws, size_t ws_size,
                              hipStream_t stream) {
    const float* x     = (const float*)d_in[0];
    const int*   adj   = (const int*)d_in[1];
    const float* fwb   = (const float*)d_in[2];
    const float* fws   = (const float*)d_in[3];
    const float* fwsc  = (const float*)d_in[4];
    const float* mwb   = (const float*)d_in[5];
    const float* mws   = (const float*)d_in[6];
    const float* mwsc  = (const float*)d_in[7];
    const float* uwb   = (const float*)d_in[8];
    const float* uws   = (const float*)d_in[9];
    const float* uwsc  = (const float*)d_in[10];
    float* out = (float*)d_out;
    float* ws = (float*)d_ws;

    const int BN = in_sizes[0] / CH;   // 512 = 2 batches x 256 rows

    msg_kernel<<<BN, 256, 0, stream>>>(x, mwb, mws, mwsc, uwb, uws, uwsc,
                                       fws, fwsc, ws);
    gat_kernel<<<BN, 256, 0, stream>>>(x, adj, fwb, ws + WS_CPAD,
                                       ws + WS_W2U, ws + WS_MSG, out);
}